// Round 15
// baseline (1922.151 us; speedup 1.0000x reference)
//
#include <hip/hip_runtime.h>
#include <math.h>

// ImuModel v13: v10 base (stride 40 LDS, fused pw epilogue, XCD barriers,
// 256 blocks x 512 thr) with ONE change: quad-buffered k-loop, TWO k-steps
// per __syncthreads (27 sync rounds instead of 54; prefetch distance 2).
// v12's stride-36 is reverted: 72B rows break 16B alignment -> b128 splits
// (1968 -> 5400 us). Lesson: LDS row stride must be a multiple of 16B;
// 2-way start-bank aliasing at stride 80B is ~free (m136).

typedef __attribute__((ext_vector_type(8))) short     bf16x8;
typedef __attribute__((ext_vector_type(8))) unsigned short u16x8;
typedef __attribute__((ext_vector_type(4))) float     f32x4;
typedef unsigned short u16;

#define RS 393216   // h-state elems per step-buffer: 4096*96

__device__ __forceinline__ float hsig(float x) {
    return fminf(fmaxf(0.2f * x + 0.5f, 0.0f), 1.0f);
}
__device__ __forceinline__ float bf2f(u16 u) {
    union { unsigned int i; float f; } v; v.i = ((unsigned int)u) << 16; return v.f;
}
__device__ __forceinline__ u16 f2bf(float f) {
    union { float f; unsigned int i; } v; v.f = f;
    unsigned int r = (v.i + 0x7FFFu + ((v.i >> 16) & 1u)) >> 16;   // RNE
    return (u16)r;
}

// ---------------- global two-level barrier (registration + fallback) --------
__device__ __forceinline__ void gridbar(unsigned* ctrs, unsigned* epoch,
                                        unsigned k, int blk)
{
    __syncthreads();
    if (threadIdx.x == 0) {
        __builtin_amdgcn_fence(__ATOMIC_RELEASE, "agent");
        __hip_atomic_fetch_add(ctrs + (blk & 63) * 64, 1u,
                               __ATOMIC_RELAXED, __HIP_MEMORY_SCOPE_AGENT);
    }
    if (blk == 0 && threadIdx.x < 64) {
        const unsigned target = k * 256u;
        unsigned sum;
        do {
            unsigned v = __hip_atomic_load(ctrs + threadIdx.x * 64,
                                           __ATOMIC_RELAXED,
                                           __HIP_MEMORY_SCOPE_AGENT);
            sum = v;
#pragma unroll
            for (int m = 1; m < 64; m <<= 1)
                sum += __shfl_xor(sum, m, 64);
            if (sum < target) __builtin_amdgcn_s_sleep(2);
        } while (sum < target);
        if (threadIdx.x == 0)
            __hip_atomic_store(epoch, k, __ATOMIC_RELAXED,
                               __HIP_MEMORY_SCOPE_AGENT);
    }
    if (threadIdx.x == 0) {
        while (__hip_atomic_load(epoch, __ATOMIC_RELAXED,
                                 __HIP_MEMORY_SCOPE_AGENT) < k)
            __builtin_amdgcn_s_sleep(4);
        __builtin_amdgcn_fence(__ATOMIC_ACQUIRE, "agent");
    }
    __syncthreads();
}

// ---------------- XCD-local barrier (v9, proven) -----------------------------
__device__ __forceinline__ void xbar(unsigned* slots, int myslot,
                                     unsigned target)
{
    __syncthreads();                  // all block stores are in L2 after this
    if (threadIdx.x == 0)
        __hip_atomic_fetch_add(slots + myslot * 32, 1u,
                               __ATOMIC_RELAXED, __HIP_MEMORY_SCOPE_AGENT);
    if (threadIdx.x < 32) {
        unsigned sum;
        do {
            unsigned v = __hip_atomic_load(slots + threadIdx.x * 32,
                                           __ATOMIC_RELAXED,
                                           __HIP_MEMORY_SCOPE_AGENT);
            sum = v;
#pragma unroll
            for (int m = 1; m < 32; m <<= 1)
                sum += __shfl_xor(sum, m, 64);
            if (sum < target) __builtin_amdgcn_s_sleep(2);
        } while (sum < target);
        asm volatile("buffer_inv sc0\n\ts_waitcnt vmcnt(0)" ::: "memory");
    }
    __syncthreads();
}

// ---------------------------------------------------------------------------
// prep kernels (gate-permuted weights)
// ---------------------------------------------------------------------------
__global__ __launch_bounds__(256) void prep_x(const float* __restrict__ x,
                                              u16* __restrict__ xpad)
{
    const int idx = blockIdx.x * 256 + threadIdx.x;      // < 262144
    const int t = idx >> 12, b = (idx >> 8) & 15, p = idx & 255;
    const float* src = x + (((size_t)b * 64 + t) * 256 + p) * 6;
    u16x8 v = {};
    v[0] = f2bf(src[0]); v[1] = f2bf(src[1]); v[2] = f2bf(src[2]);
    v[3] = f2bf(src[3]); v[4] = f2bf(src[4]); v[5] = f2bf(src[5]);
    *(u16x8*)(xpad + (size_t)idx * 8) = v;
}

__global__ __launch_bounds__(256) void wtrans0(const float* __restrict__ Wx0,
                                               const float* __restrict__ Wh0,
                                               u16* __restrict__ Wt0)
{
    const int idx = blockIdx.x * 256 + threadIdx.x;      // < 384*960
    const int n = idx / 960, k = idx - n * 960;
    const int nt = n / 96, j = n - nt * 96;
    const int no = (j / 24) * 96 + nt * 24 + (j % 24);   // permuted gate col
    float v = 0.0f;
    if (k < 96) {
        const int q = k >> 3, c = k & 7;
        if (q < 9 && c < 6) v = Wx0[(q * 6 + c) * 384 + no];
    } else {
        v = Wh0[(k - 96) * 384 + no];
    }
    Wt0[idx] = f2bf(v);
}

__global__ __launch_bounds__(256) void wtrans1(const float* __restrict__ Wx1,
                                               const float* __restrict__ Wh1,
                                               u16* __restrict__ Wt1)
{
    const int idx = blockIdx.x * 256 + threadIdx.x;      // < 384*1728
    const int n = idx / 1728, k = idx - n * 1728;
    const int nt = n / 96, j = n - nt * 96;
    const int no = (j / 24) * 96 + nt * 24 + (j % 24);   // permuted gate col
    const float v = (k < 864) ? Wx1[k * 384 + no] : Wh1[(k - 864) * 384 + no];
    Wt1[idx] = f2bf(v);
}

// Wd [1572864][10] f32 -> WdT [10][1572864] bf16
__global__ __launch_bounds__(256) void wtransD(const float* __restrict__ Wd,
                                               u16* __restrict__ WdT)
{
    const int k = blockIdx.x * 256 + threadIdx.x;        // < 1572864
    const float* src = Wd + (size_t)k * 10;
#pragma unroll
    for (int nc = 0; nc < 10; ++nc)
        WdT[(size_t)nc * 1572864 + k] = f2bf(src[nc]);
}

// ---------------------------------------------------------------------------
// one fused phase: half0 = conv1[t]+pw1[t], half1 = conv0[t+1]+pw0[t+1].
// LDS per half 51200B = 4 bufs x (A 64x40 + B 96x40 u16, 12800B each);
// accS[64][100] f32 (25600B) overlays bufs 0,1 after the k-loop.
// k-loop: 2 k-steps per sync round, staged 2 ahead in registers.
// ---------------------------------------------------------------------------
__device__ void phase(int t, int m0, int n0, int tidx, char* lds,
    const u16* __restrict__ xpad, u16* __restrict__ h0b,
    u16* __restrict__ h1b, u16* __restrict__ h0bnb, u16* __restrict__ hall,
    const u16* __restrict__ Wt0, const u16* __restrict__ Wt1,
    const float* __restrict__ b0, const float* __restrict__ b1,
    const float* __restrict__ g0, const float* __restrict__ be0,
    const float* __restrict__ mu0, const float* __restrict__ v0,
    const float* __restrict__ g1, const float* __restrict__ be1,
    const float* __restrict__ mu1, const float* __restrict__ v1,
    float (&cregs)[6])
{
    const int half = tidx >> 8;           // 0: conv1[t], 1: conv0[t+1]
    const int htid = tidx & 255;
    const bool active = half ? (t < 63) : (t >= 0);

    const u16* in0 = half ? (xpad + (size_t)(t + 1) * 32768)
                          : (h0bnb + (size_t)(t & 1) * RS);
    const u16* in1 = half ? (h0b + (size_t)(t & 1) * RS)
                          : (h1b + (size_t)((t - 1) & 1) * RS);
    u16* hraw_out = half ? (h0b + (size_t)((t + 1) & 1) * RS)
                         : (h1b + (size_t)(t & 1) * RS);
    u16* hbn_out  = half ? (h0bnb + (size_t)((t + 1) & 1) * RS)
                         : (hall + (size_t)(t < 0 ? 0 : t) * RS);

    const int lane = htid & 63;
    const int hw   = htid >> 6;
    const int wm = hw >> 1, wn = hw & 1;
    const int fr = lane & 15, fg = lane >> 4;
    const int arow = htid >> 2, seg = htid & 3;
    const int mg = m0 + arow;
    const int py = (mg >> 4) & 15, px = mg & 15, pb = mg >> 8;
    const int nt = n0 / 96;

    const int   KT   = half ? 960 : 1728;
    const int   NS0  = half ? 3   : 27;
    const int   MYST = half ? 30  : 54;
    const u16*  Wt   = half ? Wt0 : Wt1;

    // 4 buffers per half, stride 40 u16 (80B, 16B aligned)
    u16*   AsH  = (u16*)(lds + half * 51200);        // buf b: + b*6400 u16
    float* accS = (float*)(lds + half * 51200);      // [64][100] f32 (after)

    f32x4 acc[2][3];
#pragma unroll
    for (int i = 0; i < 2; ++i)
#pragma unroll
        for (int j = 0; j < 3; ++j) acc[i][j] = (f32x4){0.f, 0.f, 0.f, 0.f};

    auto stage = [&](int ks, u16x8& va, u16x8& vb0, u16x8& vb1) {
        u16x8 z = {};
        va = z;
        if (half && ks < 3) {
            const int q = ks * 4 + seg;           // 12 taps, q<9 real
            const int qd = q / 3;
            const int yy = py + qd - 1;
            const int xx = px + (q - 3 * qd) - 1;
            if (q < 9 && (unsigned)yy < 16u && (unsigned)xx < 16u)
                va = *(const u16x8*)(in0 + (size_t)((pb << 8) + yy * 16 + xx) * 8);
        } else {
            const int s = (ks < NS0) ? ks : ks - NS0;
            const u16* src = (ks < NS0) ? in0 : in1;
            const int q = s / 3;
            const int c0v = (s - 3 * q) * 32 + seg * 8;
            const int qd = q / 3;
            const int yy = py + qd - 1;
            const int xx = px + (q - 3 * qd) - 1;
            if ((unsigned)yy < 16u && (unsigned)xx < 16u)
                va = *(const u16x8*)(src + (size_t)((pb << 8) + yy * 16 + xx) * 96 + c0v);
        }
        const int koff = ks * 32 + seg * 8;
        vb0 = *(const u16x8*)(Wt + (size_t)(n0 + arow) * KT + koff);
        vb1 = z;
        if (htid < 128)
            vb1 = *(const u16x8*)(Wt + (size_t)(n0 + 64 + arow) * KT + koff);
    };
    auto ldsw = [&](int buf, u16x8& va, u16x8& vb0, u16x8& vb1) {
        u16* A = AsH + buf * 6400;
        u16* B = A + 2560;
        *(u16x8*)(A + arow * 40 + seg * 8) = va;
        *(u16x8*)(B + arow * 40 + seg * 8) = vb0;
        if (htid < 128) *(u16x8*)(B + (64 + arow) * 40 + seg * 8) = vb1;
    };
    auto dofrag = [&](int buf) {
        const u16* A = AsH + buf * 6400;
        const u16* B = A + 2560;
        bf16x8 af[2], bq[3];
#pragma unroll
        for (int mf = 0; mf < 2; ++mf)
            af[mf] = *(const bf16x8*)(A + (wm * 32 + mf * 16 + fr) * 40 + fg * 8);
#pragma unroll
        for (int nf = 0; nf < 3; ++nf)
            bq[nf] = *(const bf16x8*)(B + (wn * 48 + nf * 16 + fr) * 40 + fg * 8);

        __builtin_amdgcn_s_setprio(1);
#pragma unroll
        for (int mf = 0; mf < 2; ++mf)
#pragma unroll
            for (int nf = 0; nf < 3; ++nf)
                acc[mf][nf] = __builtin_amdgcn_mfma_f32_16x16x32_bf16(
                    af[mf], bq[nf], acc[mf][nf], 0, 0, 0);
        __builtin_amdgcn_s_setprio(0);
    };

    u16x8 vaA, vb0A, vb1A, vaB, vb0B, vb1B;

    if (active) {
        stage(0, vaA, vb0A, vb1A);
        stage(1, vaB, vb0B, vb1B);
        ldsw(0, vaA, vb0A, vb1A);
        ldsw(1, vaB, vb0B, vb1B);
    }
    __syncthreads();

    // 27 lockstep super-iterations (conv0 half active for first 15)
    for (int j = 0; j < 27; ++j) {
        const int ks = 2 * j;
        if (active && ks < MYST) {
            const bool more = (ks + 2 < MYST);
            if (more) {
                stage(ks + 2, vaA, vb0A, vb1A);   // loads fly under 12 MFMAs
                stage(ks + 3, vaB, vb0B, vb1B);
            }
            dofrag(ks & 3);
            dofrag((ks + 1) & 3);
            if (more) {
                ldsw((ks + 2) & 3, vaA, vb0A, vb1A);
                ldsw((ks + 3) & 3, vaB, vb0B, vb1B);
            }
        }
        __syncthreads();   // common site for both halves
    }
    // k-loop done; bufs dead -> recycle first 25600B as accS.

    // E1: acc + bias -> accS[row][col]
    if (active) {
        const float* bias = half ? b0 : b1;
#pragma unroll
        for (int nf = 0; nf < 3; ++nf) {
            const int col = wn * 48 + nf * 16 + fr;
            const float bi = bias[(col / 24) * 96 + nt * 24 + (col % 24)];
#pragma unroll
            for (int mf = 0; mf < 2; ++mf) {
                const int row = wm * 32 + mf * 16 + fg * 4;
#pragma unroll
                for (int r = 0; r < 4; ++r)
                    accS[(row + r) * 100 + col] = acc[mf][nf][r] + bi;
            }
        }
    }
    __syncthreads();

    // E2: LSTM pointwise + BN, c in registers, h/hbn to global (parity bufs)
    if (active) {
        const float* gam = half ? g0 : g1;
        const float* bet = half ? be0 : be1;
        const float* muv = half ? mu0 : mu1;
        const float* var = half ? v0  : v1;
#pragma unroll
        for (int q = 0; q < 6; ++q) {
            const int item = htid + 256 * q;          // < 1536
            const int r = item / 24, fl = item - r * 24;
            const float gi = accS[r * 100 + fl];
            const float gf = accS[r * 100 + 24 + fl];
            const float gc = accS[r * 100 + 48 + fl];
            const float go = accS[r * 100 + 72 + fl];
            const int f = nt * 24 + fl;
            const float i_ = hsig(gi);
            const float f_ = hsig(gf);
            const float o_ = hsig(go);
            const float c_ = f_ * cregs[q] + i_ * tanhf(gc);
            const float h_ = o_ * tanhf(c_);
            cregs[q] = c_;
            hraw_out[(size_t)(m0 + r) * 96 + f] = f2bf(h_);
            const float s = gam[f] * rsqrtf(var[f] + 1e-3f);
            hbn_out[(size_t)(m0 + r) * 96 + f] =
                f2bf((h_ - muv[f]) * s + bet[f]);
        }
    }
    // caller's barrier orders accS reads vs next phase
}

// ---------------------------------------------------------------------------
// persistent kernel: XCD-grouped if placement allows, else global barriers
// ---------------------------------------------------------------------------
__global__ __launch_bounds__(512, 2) void fused(
    unsigned* bctrs, unsigned* bepoch, unsigned* reg8, unsigned* xslots,
    const u16* xpad, u16* h0b, u16* h1b, u16* h0bnb, u16* hall,
    const u16* Wt0, const u16* Wt1,
    const float* b0, const float* b1,
    const float* g0, const float* be0, const float* mu0, const float* v0,
    const float* g1, const float* be1, const float* mu1, const float* v1)
{
    __shared__ char lds[102400];
    __shared__ unsigned shinfo[3];      // xcc, slot, ok
    const int blk = blockIdx.x;

    if (threadIdx.x == 0) {
        unsigned xcc;
        asm volatile("s_getreg_b32 %0, hwreg(HW_REG_XCC_ID)" : "=s"(xcc));
        xcc &= 7u;
        unsigned slot = __hip_atomic_fetch_add(reg8 + xcc * 64, 1u,
                                               __ATOMIC_RELAXED,
                                               __HIP_MEMORY_SCOPE_AGENT);
        shinfo[0] = xcc; shinfo[1] = slot;
    }
    gridbar(bctrs, bepoch, 1, blk);     // registration settled device-wide
    if (threadIdx.x == 0) {
        unsigned ok = 1;
#pragma unroll
        for (int k = 0; k < 8; ++k)
            ok &= (__hip_atomic_load(reg8 + k * 64, __ATOMIC_RELAXED,
                                     __HIP_MEMORY_SCOPE_AGENT) == 32u);
        shinfo[2] = ok;
    }
    __syncthreads();
    const unsigned grp  = shinfo[0];
    const unsigned slot = shinfo[1];
    const bool grouped  = (shinfo[2] != 0u);

    float cregs[6] = {0.f, 0.f, 0.f, 0.f, 0.f, 0.f};

    if (grouped) {
        const int m0 = (int)grp * 512 + (int)(slot >> 2) * 64;
        const int n0 = (int)(slot & 3) * 96;
        unsigned* gs = xslots + grp * 1024;
        unsigned bar = 0;
        for (int t = -1; t < 64; ++t) {
            phase(t, m0, n0, threadIdx.x, lds, xpad, h0b, h1b, h0bnb, hall,
                  Wt0, Wt1, b0, b1, g0, be0, mu0, v0, g1, be1, mu1, v1, cregs);
            xbar(gs, (int)slot, (++bar) * 32u);
        }
    } else {
        const int m0 = (blk >> 2) * 64;
        const int n0 = (blk & 3) * 96;
        unsigned bar = 1;                   // epoch 1 used by registration
        for (int t = -1; t < 64; ++t) {
            phase(t, m0, n0, threadIdx.x, lds, xpad, h0b, h1b, h0bnb, hall,
                  Wt0, Wt1, b0, b1, g0, be0, mu0, v0, g1, be1, mu1, v1, cregs);
            gridbar(bctrs, bepoch, ++bar, blk);
        }
    }
}

// ---------------------------------------------------------------------------
// launch-fallback per-step kernel (c-state round-trips through global)
// ---------------------------------------------------------------------------
__global__ __launch_bounds__(512, 2) void stepF(int t,
    const u16* xpad, u16* h0b, u16* h1b, u16* h0bnb, u16* hall,
    const u16* Wt0, const u16* Wt1,
    const float* b0, const float* b1,
    const float* g0, const float* be0, const float* mu0, const float* v0,
    const float* g1, const float* be1, const float* mu1, const float* v1,
    float* c0g, float* c1g)
{
    __shared__ char lds[102400];
    const int m0 = (blockIdx.x >> 2) * 64;
    const int n0 = (blockIdx.x & 3) * 96;
    const int half = threadIdx.x >> 8;
    const int htid = threadIdx.x & 255;
    const int nt = n0 / 96;
    float* cst = half ? c0g : c1g;

    float cregs[6];
#pragma unroll
    for (int q = 0; q < 6; ++q) {
        const int item = htid + 256 * q;
        const int r = item / 24, fl = item - r * 24;
        cregs[q] = cst[(size_t)(m0 + r) * 96 + nt * 24 + fl];
    }
    phase(t, m0, n0, threadIdx.x, lds, xpad, h0b, h1b, h0bnb, hall,
          Wt0, Wt1, b0, b1, g0, be0, mu0, v0, g1, be1, mu1, v1, cregs);
#pragma unroll
    for (int q = 0; q < 6; ++q) {
        const int item = htid + 256 * q;
        const int r = item / 24, fl = item - r * 24;
        cst[(size_t)(m0 + r) * 96 + nt * 24 + fl] = cregs[q];
    }
}

// ---------------------------------------------------------------------------
// dense tail: bf16 x bf16, both operands contiguous
// ---------------------------------------------------------------------------
__global__ void dense_partial(const u16* __restrict__ hall,
                              const u16* __restrict__ WdT,
                              float* __restrict__ partial)
{
    const int k0 = blockIdx.x * 2048;
    const int tt = k0 / 24576;
    const int r0 = k0 - tt * 24576;
    const int th = threadIdx.x;          // 0..159
    const int b  = th / 10;
    const int nc = th - b * 10;
    const u16* hp = hall + (size_t)(tt * 16 + b) * 24576 + r0;
    const u16* wp = WdT + (size_t)nc * 1572864 + k0;
    float acc = 0.0f;
    for (int j = 0; j < 2048; j += 8) {
        const u16x8 hv = *(const u16x8*)(hp + j);
        const u16x8 wv = *(const u16x8*)(wp + j);
#pragma unroll
        for (int u = 0; u < 8; ++u)
            acc = fmaf(bf2f(hv[u]), bf2f(wv[u]), acc);
    }
    partial[blockIdx.x * 160 + th] = acc;
}

__global__ void dense_reduce(const float* __restrict__ partial,
                             const float* __restrict__ bd,
                             float* __restrict__ out)
{
    const int t = threadIdx.x;           // 0..159
    const int nc = t - (t / 10) * 10;
    float acc = bd[nc];
    for (int p = 0; p < 768; ++p) acc += partial[p * 160 + t];
    out[t] = acc;
}

// ---------------------------------------------------------------------------
extern "C" void kernel_launch(void* const* d_in, const int* in_sizes, int n_in,
                              void* d_out, int out_size, void* d_ws, size_t ws_size,
                              hipStream_t stream)
{
    const float* x    = (const float*)d_in[0];
    const float* Wx0  = (const float*)d_in[1];
    const float* Wh0  = (const float*)d_in[2];
    const float* b0p  = (const float*)d_in[3];
    const float* g0p  = (const float*)d_in[4];
    const float* be0p = (const float*)d_in[5];
    const float* mu0p = (const float*)d_in[6];
    const float* v0p  = (const float*)d_in[7];
    const float* Wx1  = (const float*)d_in[8];
    const float* Wh1  = (const float*)d_in[9];
    const float* b1p  = (const float*)d_in[10];
    const float* g1p  = (const float*)d_in[11];
    const float* be1p = (const float*)d_in[12];
    const float* mu1p = (const float*)d_in[13];
    const float* v1p  = (const float*)d_in[14];
    const float* Wd   = (const float*)d_in[15];
    const float* bd   = (const float*)d_in[16];
    float* out = (float*)d_out;

    char* base = (char*)d_ws;
    u16*   h0b    = (u16*)(base);                      //  1572864 B (2 par)
    u16*   h1b    = (u16*)(base + 1572864);            //  1572864 B
    u16*   h0bnb  = (u16*)(base + 3145728);            //  1572864 B
    float* c0g    = (float*)(base + 4718592);          //  1572864 B (fallback)
    float* c1g    = (float*)(base + 6291456);          //  1572864 B
    u16*   xpad   = (u16*)(base + 7864320);            //  4194304 B
    u16*   Wt0    = (u16*)(base + 12058624);           //   737280 B
    u16*   Wt1    = (u16*)(base + 12795904);           //  1327104 B
    u16*   hall   = (u16*)(base + 14123008);           // 50331648 B
    float* part   = (float*)(base + 64454656);         //   491520 B
    u16*   WdT    = (u16*)(base + 64946176);           // 31457280 B
    unsigned* bctrs  = (unsigned*)(base + 96403456);   //    16384 B
    unsigned* bepoch = (unsigned*)(base + 96419840);   //      256 B
    unsigned* reg8   = (unsigned*)(base + 96420096);   //     2048 B
    unsigned* xslots = (unsigned*)(base + 96422144);   //    32768 B

    hipMemsetAsync(base, 0, 7864320, stream);          // h/hbn/c states = 0
    hipMemsetAsync(bctrs, 0, 51456, stream);           // all barrier state

    prep_x <<<1024, 256, 0, stream>>>(x, xpad);
    wtrans0<<<1440, 256, 0, stream>>>(Wx0, Wh0, Wt0);
    wtrans1<<<2592, 256, 0, stream>>>(Wx1, Wh1, Wt1);
    wtransD<<<6144, 256, 0, stream>>>(Wd, WdT);

    void* args[] = {
        (void*)&bctrs, (void*)&bepoch, (void*)&reg8, (void*)&xslots,
        (void*)&xpad, (void*)&h0b, (void*)&h1b, (void*)&h0bnb, (void*)&hall,
        (void*)&Wt0, (void*)&Wt1, (void*)&b0p, (void*)&b1p,
        (void*)&g0p, (void*)&be0p, (void*)&mu0p, (void*)&v0p,
        (void*)&g1p, (void*)&be1p, (void*)&mu1p, (void*)&v1p
    };
    hipError_t ce = hipLaunchCooperativeKernel((void*)fused, dim3(256),
                                               dim3(512), args, 0, stream);
    if (ce != hipSuccess) {
        (void)hipGetLastError();   // clear sticky error, use fallback path
        for (int t = -1; t < 64; ++t) {
            stepF<<<256, 512, 0, stream>>>(t, xpad, h0b, h1b, h0bnb, hall,
                                           Wt0, Wt1, b0p, b1p,
                                           g0p, be0p, mu0p, v0p,
                                           g1p, be1p, mu1p, v1p, c0g, c1g);
        }
    }

    dense_partial<<<768, 160, 0, stream>>>(hall, WdT, part);
    dense_reduce <<<1, 160, 0, stream>>>(part, bd, out);
}

// Round 16
// 1743.473 us; speedup vs baseline: 1.1025x; 1.1025x over previous
//
#include <hip/hip_runtime.h>
#include <math.h>

// ImuModel v16: v13 base minus B-through-LDS.
// B (weights) now lives in a pre-swizzled FRAGMENT-ORDER global layout
// WtF[nt][ks][wn][nf][lane][8]: each MFMA B-frag is one fully-coalesced
// 1KB load (64 lanes x contiguous 16B), L2-resident, wm-pair reuse hits L1.
// Deletes B LDS writes+reads (30KB -> 12KB LDS per k-step) and B staging
// VALU. A path / quad-buffer / fused pw epilogue / XCD barriers = v13.
// launch_bounds (512,1): grid is 256 blocks = 1/CU; old (512,2) only
// capped VGPRs (B reg pipeline needs ~48 more).

typedef __attribute__((ext_vector_type(8))) short     bf16x8;
typedef __attribute__((ext_vector_type(8))) unsigned short u16x8;
typedef __attribute__((ext_vector_type(4))) float     f32x4;
typedef unsigned short u16;

#define RS 393216   // h-state elems per step-buffer: 4096*96

__device__ __forceinline__ float hsig(float x) {
    return fminf(fmaxf(0.2f * x + 0.5f, 0.0f), 1.0f);
}
__device__ __forceinline__ float bf2f(u16 u) {
    union { unsigned int i; float f; } v; v.i = ((unsigned int)u) << 16; return v.f;
}
__device__ __forceinline__ u16 f2bf(float f) {
    union { float f; unsigned int i; } v; v.f = f;
    unsigned int r = (v.i + 0x7FFFu + ((v.i >> 16) & 1u)) >> 16;   // RNE
    return (u16)r;
}

// ---------------- global two-level barrier (registration + fallback) --------
__device__ __forceinline__ void gridbar(unsigned* ctrs, unsigned* epoch,
                                        unsigned k, int blk)
{
    __syncthreads();
    if (threadIdx.x == 0) {
        __builtin_amdgcn_fence(__ATOMIC_RELEASE, "agent");
        __hip_atomic_fetch_add(ctrs + (blk & 63) * 64, 1u,
                               __ATOMIC_RELAXED, __HIP_MEMORY_SCOPE_AGENT);
    }
    if (blk == 0 && threadIdx.x < 64) {
        const unsigned target = k * 256u;
        unsigned sum;
        do {
            unsigned v = __hip_atomic_load(ctrs + threadIdx.x * 64,
                                           __ATOMIC_RELAXED,
                                           __HIP_MEMORY_SCOPE_AGENT);
            sum = v;
#pragma unroll
            for (int m = 1; m < 64; m <<= 1)
                sum += __shfl_xor(sum, m, 64);
            if (sum < target) __builtin_amdgcn_s_sleep(2);
        } while (sum < target);
        if (threadIdx.x == 0)
            __hip_atomic_store(epoch, k, __ATOMIC_RELAXED,
                               __HIP_MEMORY_SCOPE_AGENT);
    }
    if (threadIdx.x == 0) {
        while (__hip_atomic_load(epoch, __ATOMIC_RELAXED,
                                 __HIP_MEMORY_SCOPE_AGENT) < k)
            __builtin_amdgcn_s_sleep(4);
        __builtin_amdgcn_fence(__ATOMIC_ACQUIRE, "agent");
    }
    __syncthreads();
}

// ---------------- XCD-local barrier (v9, proven) -----------------------------
__device__ __forceinline__ void xbar(unsigned* slots, int myslot,
                                     unsigned target)
{
    __syncthreads();                  // all block stores are in L2 after this
    if (threadIdx.x == 0)
        __hip_atomic_fetch_add(slots + myslot * 32, 1u,
                               __ATOMIC_RELAXED, __HIP_MEMORY_SCOPE_AGENT);
    if (threadIdx.x < 32) {
        unsigned sum;
        do {
            unsigned v = __hip_atomic_load(slots + threadIdx.x * 32,
                                           __ATOMIC_RELAXED,
                                           __HIP_MEMORY_SCOPE_AGENT);
            sum = v;
#pragma unroll
            for (int m = 1; m < 32; m <<= 1)
                sum += __shfl_xor(sum, m, 64);
            if (sum < target) __builtin_amdgcn_s_sleep(2);
        } while (sum < target);
        asm volatile("buffer_inv sc0\n\ts_waitcnt vmcnt(0)" ::: "memory");
    }
    __syncthreads();
}

// ---------------------------------------------------------------------------
// prep kernels. Weights go to fragment-order layout:
// WtF[nt][ks][wn][nf][lane][e]:  fr=lane&15, fg=lane>>4,
//   n_local = wn*48+nf*16+fr, gate-permuted col no, k = ks*32+fg*8+e.
// ---------------------------------------------------------------------------
__global__ __launch_bounds__(256) void prep_x(const float* __restrict__ x,
                                              u16* __restrict__ xpad)
{
    const int idx = blockIdx.x * 256 + threadIdx.x;      // < 262144
    const int t = idx >> 12, b = (idx >> 8) & 15, p = idx & 255;
    const float* src = x + (((size_t)b * 64 + t) * 256 + p) * 6;
    u16x8 v = {};
    v[0] = f2bf(src[0]); v[1] = f2bf(src[1]); v[2] = f2bf(src[2]);
    v[3] = f2bf(src[3]); v[4] = f2bf(src[4]); v[5] = f2bf(src[5]);
    *(u16x8*)(xpad + (size_t)idx * 8) = v;
}

__global__ __launch_bounds__(256) void wtransF0(const float* __restrict__ Wx0,
                                                const float* __restrict__ Wh0,
                                                u16* __restrict__ W)
{
    const int idx = blockIdx.x * 256 + threadIdx.x;      // < 368640
    const int e = idx & 7;
    const int lane = (idx >> 3) & 63;
    int r = idx >> 9;
    const int nf = r % 3; r /= 3;
    const int wn = r & 1; r >>= 1;
    const int ks = r % 30;
    const int nt = r / 30;
    const int fr = lane & 15, fg = lane >> 4;
    const int jl = wn * 48 + nf * 16 + fr;               // n_local 0..95
    const int no = (jl / 24) * 96 + nt * 24 + (jl % 24); // gate-permuted col
    const int k = ks * 32 + fg * 8 + e;                  // 0..959
    float v = 0.0f;
    if (k < 96) {
        const int q = k >> 3, c = k & 7;
        if (q < 9 && c < 6) v = Wx0[(q * 6 + c) * 384 + no];
    } else {
        v = Wh0[(k - 96) * 384 + no];
    }
    W[idx] = f2bf(v);
}

__global__ __launch_bounds__(256) void wtransF1(const float* __restrict__ Wx1,
                                                const float* __restrict__ Wh1,
                                                u16* __restrict__ W)
{
    const int idx = blockIdx.x * 256 + threadIdx.x;      // < 663552
    const int e = idx & 7;
    const int lane = (idx >> 3) & 63;
    int r = idx >> 9;
    const int nf = r % 3; r /= 3;
    const int wn = r & 1; r >>= 1;
    const int ks = r % 54;
    const int nt = r / 54;
    const int fr = lane & 15, fg = lane >> 4;
    const int jl = wn * 48 + nf * 16 + fr;
    const int no = (jl / 24) * 96 + nt * 24 + (jl % 24);
    const int k = ks * 32 + fg * 8 + e;                  // 0..1727
    const float v = (k < 864) ? Wx1[k * 384 + no] : Wh1[(k - 864) * 384 + no];
    W[idx] = f2bf(v);
}

// Wd [1572864][10] f32 -> WdT [10][1572864] bf16
__global__ __launch_bounds__(256) void wtransD(const float* __restrict__ Wd,
                                               u16* __restrict__ WdT)
{
    const int k = blockIdx.x * 256 + threadIdx.x;        // < 1572864
    const float* src = Wd + (size_t)k * 10;
#pragma unroll
    for (int nc = 0; nc < 10; ++nc)
        WdT[(size_t)nc * 1572864 + k] = f2bf(src[nc]);
}

// ---------------------------------------------------------------------------
// one fused phase: half0 = conv1[t]+pw1[t], half1 = conv0[t+1]+pw0[t+1].
// LDS per half 25600B = union{ A quad-buffer 4 x [64][40] u16 (20480B),
//                              accS[64][100] f32 (25600B) }.
// B: direct global frag loads (WtF), 2-super-iter register pipeline.
// ---------------------------------------------------------------------------
__device__ void phase(int t, int m0, int n0, int tidx, char* lds,
    const u16* __restrict__ xpad, u16* __restrict__ h0b,
    u16* __restrict__ h1b, u16* __restrict__ h0bnb, u16* __restrict__ hall,
    const u16* __restrict__ WtF0, const u16* __restrict__ WtF1,
    const float* __restrict__ b0, const float* __restrict__ b1,
    const float* __restrict__ g0, const float* __restrict__ be0,
    const float* __restrict__ mu0, const float* __restrict__ v0,
    const float* __restrict__ g1, const float* __restrict__ be1,
    const float* __restrict__ mu1, const float* __restrict__ v1,
    float (&cregs)[6])
{
    const int half = tidx >> 8;           // 0: conv1[t], 1: conv0[t+1]
    const int htid = tidx & 255;
    const bool active = half ? (t < 63) : (t >= 0);

    const u16* in0 = half ? (xpad + (size_t)(t + 1) * 32768)
                          : (h0bnb + (size_t)(t & 1) * RS);
    const u16* in1 = half ? (h0b + (size_t)(t & 1) * RS)
                          : (h1b + (size_t)((t - 1) & 1) * RS);
    u16* hraw_out = half ? (h0b + (size_t)((t + 1) & 1) * RS)
                         : (h1b + (size_t)(t & 1) * RS);
    u16* hbn_out  = half ? (h0bnb + (size_t)((t + 1) & 1) * RS)
                         : (hall + (size_t)(t < 0 ? 0 : t) * RS);

    const int lane = htid & 63;
    const int hw   = htid >> 6;
    const int wm = hw >> 1, wn = hw & 1;
    const int fr = lane & 15, fg = lane >> 4;
    const int arow = htid >> 2, seg = htid & 3;
    const int mg = m0 + arow;
    const int py = (mg >> 4) & 15, px = mg & 15, pb = mg >> 8;
    const int nt = n0 / 96;

    const int   NS0  = half ? 3   : 27;
    const int   MYST = half ? 30  : 54;   // == KS of this conv
    // fragment-order B base for this (nt, wn, lane)
    const u16*  Bp   = (half ? WtF0 : WtF1)
                       + (size_t)nt * (MYST * 3072) + wn * 1536 + (lane << 3);

    u16*   AsH  = (u16*)(lds + half * 25600);        // 4 bufs x 2560 u16
    float* accS = (float*)(lds + half * 25600);      // [64][100] f32 (after)

    f32x4 acc[2][3];
#pragma unroll
    for (int i = 0; i < 2; ++i)
#pragma unroll
        for (int j = 0; j < 3; ++j) acc[i][j] = (f32x4){0.f, 0.f, 0.f, 0.f};

    auto stageA = [&](int ks, u16x8& va) {
        u16x8 z = {};
        va = z;
        if (half && ks < 3) {
            const int q = ks * 4 + seg;           // 12 taps, q<9 real
            const int qd = q / 3;
            const int yy = py + qd - 1;
            const int xx = px + (q - 3 * qd) - 1;
            if (q < 9 && (unsigned)yy < 16u && (unsigned)xx < 16u)
                va = *(const u16x8*)(in0 + (size_t)((pb << 8) + yy * 16 + xx) * 8);
        } else {
            const int s = (ks < NS0) ? ks : ks - NS0;
            const u16* src = (ks < NS0) ? in0 : in1;
            const int q = s / 3;
            const int c0v = (s - 3 * q) * 32 + seg * 8;
            const int qd = q / 3;
            const int yy = py + qd - 1;
            const int xx = px + (q - 3 * qd) - 1;
            if ((unsigned)yy < 16u && (unsigned)xx < 16u)
                va = *(const u16x8*)(src + (size_t)((pb << 8) + yy * 16 + xx) * 96 + c0v);
        }
    };
    auto ldswA = [&](int buf, u16x8& va) {
        *(u16x8*)(AsH + buf * 2560 + arow * 40 + seg * 8) = va;
    };
    auto loadB = [&](int ks, bf16x8 (&bq)[3]) {
#pragma unroll
        for (int nf = 0; nf < 3; ++nf)
            bq[nf] = *(const bf16x8*)(Bp + ks * 3072 + nf * 512);
    };
    auto dofrag = [&](int buf, bf16x8 (&bq)[3]) {
        const u16* A = AsH + buf * 2560;
        bf16x8 af[2];
#pragma unroll
        for (int mf = 0; mf < 2; ++mf)
            af[mf] = *(const bf16x8*)(A + (wm * 32 + mf * 16 + fr) * 40 + fg * 8);

        __builtin_amdgcn_s_setprio(1);
#pragma unroll
        for (int mf = 0; mf < 2; ++mf)
#pragma unroll
            for (int nf = 0; nf < 3; ++nf)
                acc[mf][nf] = __builtin_amdgcn_mfma_f32_16x16x32_bf16(
                    af[mf], bq[nf], acc[mf][nf], 0, 0, 0);
        __builtin_amdgcn_s_setprio(0);
    };

    u16x8 vaA, vaB;
    bf16x8 bqE[3], bqO[3], tE[3], tO[3];

    if (active) {
        stageA(0, vaA); stageA(1, vaB);
        ldswA(0, vaA);  ldswA(1, vaB);
        loadB(0, bqE);  loadB(1, bqO);
    }
    __syncthreads();

    // 27 lockstep super-iterations (conv0 half active for first 15)
    for (int j = 0; j < 27; ++j) {
        const int ks = 2 * j;
        if (active && ks < MYST) {
            const bool more = (ks + 2 < MYST);
            if (more) {
                stageA(ks + 2, vaA);    // A loads fly under 12 MFMAs
                stageA(ks + 3, vaB);
                loadB(ks + 2, tE);      // B frag loads (coalesced, L2/L1)
                loadB(ks + 3, tO);
            }
            dofrag(ks & 3, bqE);
            dofrag((ks + 1) & 3, bqO);
            if (more) {
                ldswA((ks + 2) & 3, vaA);
                ldswA((ks + 3) & 3, vaB);
#pragma unroll
                for (int nf = 0; nf < 3; ++nf) {
                    bqE[nf] = tE[nf];
                    bqO[nf] = tO[nf];
                }
            }
        }
        __syncthreads();   // common site for both halves
    }
    // k-loop done; A bufs dead -> recycle as accS.

    // E1: acc + bias -> accS[row][col]
    if (active) {
        const float* bias = half ? b0 : b1;
#pragma unroll
        for (int nf = 0; nf < 3; ++nf) {
            const int col = wn * 48 + nf * 16 + fr;
            const float bi = bias[(col / 24) * 96 + nt * 24 + (col % 24)];
#pragma unroll
            for (int mf = 0; mf < 2; ++mf) {
                const int row = wm * 32 + mf * 16 + fg * 4;
#pragma unroll
                for (int r = 0; r < 4; ++r)
                    accS[(row + r) * 100 + col] = acc[mf][nf][r] + bi;
            }
        }
    }
    __syncthreads();

    // E2: LSTM pointwise + BN, c in registers, h/hbn to global (parity bufs)
    if (active) {
        const float* gam = half ? g0 : g1;
        const float* bet = half ? be0 : be1;
        const float* muv = half ? mu0 : mu1;
        const float* var = half ? v0  : v1;
#pragma unroll
        for (int q = 0; q < 6; ++q) {
            const int item = htid + 256 * q;          // < 1536
            const int r = item / 24, fl = item - r * 24;
            const float gi = accS[r * 100 + fl];
            const float gf = accS[r * 100 + 24 + fl];
            const float gc = accS[r * 100 + 48 + fl];
            const float go = accS[r * 100 + 72 + fl];
            const int f = nt * 24 + fl;
            const float i_ = hsig(gi);
            const float f_ = hsig(gf);
            const float o_ = hsig(go);
            const float c_ = f_ * cregs[q] + i_ * tanhf(gc);
            const float h_ = o_ * tanhf(c_);
            cregs[q] = c_;
            hraw_out[(size_t)(m0 + r) * 96 + f] = f2bf(h_);
            const float s = gam[f] * rsqrtf(var[f] + 1e-3f);
            hbn_out[(size_t)(m0 + r) * 96 + f] =
                f2bf((h_ - muv[f]) * s + bet[f]);
        }
    }
    // caller's barrier orders accS reads vs next phase
}

// ---------------------------------------------------------------------------
// persistent kernel: XCD-grouped if placement allows, else global barriers
// ---------------------------------------------------------------------------
__global__ __launch_bounds__(512, 1) void fused(
    unsigned* bctrs, unsigned* bepoch, unsigned* reg8, unsigned* xslots,
    const u16* xpad, u16* h0b, u16* h1b, u16* h0bnb, u16* hall,
    const u16* WtF0, const u16* WtF1,
    const float* b0, const float* b1,
    const float* g0, const float* be0, const float* mu0, const float* v0,
    const float* g1, const float* be1, const float* mu1, const float* v1)
{
    __shared__ char lds[51200];
    __shared__ unsigned shinfo[3];      // xcc, slot, ok
    const int blk = blockIdx.x;

    if (threadIdx.x == 0) {
        unsigned xcc;
        asm volatile("s_getreg_b32 %0, hwreg(HW_REG_XCC_ID)" : "=s"(xcc));
        xcc &= 7u;
        unsigned slot = __hip_atomic_fetch_add(reg8 + xcc * 64, 1u,
                                               __ATOMIC_RELAXED,
                                               __HIP_MEMORY_SCOPE_AGENT);
        shinfo[0] = xcc; shinfo[1] = slot;
    }
    gridbar(bctrs, bepoch, 1, blk);     // registration settled device-wide
    if (threadIdx.x == 0) {
        unsigned ok = 1;
#pragma unroll
        for (int k = 0; k < 8; ++k)
            ok &= (__hip_atomic_load(reg8 + k * 64, __ATOMIC_RELAXED,
                                     __HIP_MEMORY_SCOPE_AGENT) == 32u);
        shinfo[2] = ok;
    }
    __syncthreads();
    const unsigned grp  = shinfo[0];
    const unsigned slot = shinfo[1];
    const bool grouped  = (shinfo[2] != 0u);

    float cregs[6] = {0.f, 0.f, 0.f, 0.f, 0.f, 0.f};

    if (grouped) {
        const int m0 = (int)grp * 512 + (int)(slot >> 2) * 64;
        const int n0 = (int)(slot & 3) * 96;
        unsigned* gs = xslots + grp * 1024;
        unsigned bar = 0;
        for (int t = -1; t < 64; ++t) {
            phase(t, m0, n0, threadIdx.x, lds, xpad, h0b, h1b, h0bnb, hall,
                  WtF0, WtF1, b0, b1, g0, be0, mu0, v0, g1, be1, mu1, v1,
                  cregs);
            xbar(gs, (int)slot, (++bar) * 32u);
        }
    } else {
        const int m0 = (blk >> 2) * 64;
        const int n0 = (blk & 3) * 96;
        unsigned bar = 1;                   // epoch 1 used by registration
        for (int t = -1; t < 64; ++t) {
            phase(t, m0, n0, threadIdx.x, lds, xpad, h0b, h1b, h0bnb, hall,
                  WtF0, WtF1, b0, b1, g0, be0, mu0, v0, g1, be1, mu1, v1,
                  cregs);
            gridbar(bctrs, bepoch, ++bar, blk);
        }
    }
}

// ---------------------------------------------------------------------------
// launch-fallback per-step kernel (c-state round-trips through global)
// ---------------------------------------------------------------------------
__global__ __launch_bounds__(512, 1) void stepF(int t,
    const u16* xpad, u16* h0b, u16* h1b, u16* h0bnb, u16* hall,
    const u16* WtF0, const u16* WtF1,
    const float* b0, const float* b1,
    const float* g0, const float* be0, const float* mu0, const float* v0,
    const float* g1, const float* be1, const float* mu1, const float* v1,
    float* c0g, float* c1g)
{
    __shared__ char lds[51200];
    const int m0 = (blockIdx.x >> 2) * 64;
    const int n0 = (blockIdx.x & 3) * 96;
    const int half = threadIdx.x >> 8;
    const int htid = threadIdx.x & 255;
    const int nt = n0 / 96;
    float* cst = half ? c0g : c1g;

    float cregs[6];
#pragma unroll
    for (int q = 0; q < 6; ++q) {
        const int item = htid + 256 * q;
        const int r = item / 24, fl = item - r * 24;
        cregs[q] = cst[(size_t)(m0 + r) * 96 + nt * 24 + fl];
    }
    phase(t, m0, n0, threadIdx.x, lds, xpad, h0b, h1b, h0bnb, hall,
          WtF0, WtF1, b0, b1, g0, be0, mu0, v0, g1, be1, mu1, v1, cregs);
#pragma unroll
    for (int q = 0; q < 6; ++q) {
        const int item = htid + 256 * q;
        const int r = item / 24, fl = item - r * 24;
        cst[(size_t)(m0 + r) * 96 + nt * 24 + fl] = cregs[q];
    }
}

// ---------------------------------------------------------------------------
// dense tail: bf16 x bf16, both operands contiguous
// ---------------------------------------------------------------------------
__global__ void dense_partial(const u16* __restrict__ hall,
                              const u16* __restrict__ WdT,
                              float* __restrict__ partial)
{
    const int k0 = blockIdx.x * 2048;
    const int tt = k0 / 24576;
    const int r0 = k0 - tt * 24576;
    const int th = threadIdx.x;          // 0..159
    const int b  = th / 10;
    const int nc = th - b * 10;
    const u16* hp = hall + (size_t)(tt * 16 + b) * 24576 + r0;
    const u16* wp = WdT + (size_t)nc * 1572864 + k0;
    float acc = 0.0f;
    for (int j = 0; j < 2048; j += 8) {
        const u16x8 hv = *(const u16x8*)(hp + j);
        const u16x8 wv = *(const u16x8*)(wp + j);
#pragma unroll
        for (int u = 0; u < 8; ++u)
            acc = fmaf(bf2f(hv[u]), bf2f(wv[u]), acc);
    }
    partial[blockIdx.x * 160 + th] = acc;
}

__global__ void dense_reduce(const float* __restrict__ partial,
                             const float* __restrict__ bd,
                             float* __restrict__ out)
{
    const int t = threadIdx.x;           // 0..159
    const int nc = t - (t / 10) * 10;
    float acc = bd[nc];
    for (int p = 0; p < 768; ++p) acc += partial[p * 160 + t];
    out[t] = acc;
}

// ---------------------------------------------------------------------------
extern "C" void kernel_launch(void* const* d_in, const int* in_sizes, int n_in,
                              void* d_out, int out_size, void* d_ws, size_t ws_size,
                              hipStream_t stream)
{
    const float* x    = (const float*)d_in[0];
    const float* Wx0  = (const float*)d_in[1];
    const float* Wh0  = (const float*)d_in[2];
    const float* b0p  = (const float*)d_in[3];
    const float* g0p  = (const float*)d_in[4];
    const float* be0p = (const float*)d_in[5];
    const float* mu0p = (const float*)d_in[6];
    const float* v0p  = (const float*)d_in[7];
    const float* Wx1  = (const float*)d_in[8];
    const float* Wh1  = (const float*)d_in[9];
    const float* b1p  = (const float*)d_in[10];
    const float* g1p  = (const float*)d_in[11];
    const float* be1p = (const float*)d_in[12];
    const float* mu1p = (const float*)d_in[13];
    const float* v1p  = (const float*)d_in[14];
    const float* Wd   = (const float*)d_in[15];
    const float* bd   = (const float*)d_in[16];
    float* out = (float*)d_out;

    char* base = (char*)d_ws;
    u16*   h0b    = (u16*)(base);                      //  1572864 B (2 par)
    u16*   h1b    = (u16*)(base + 1572864);            //  1572864 B
    u16*   h0bnb  = (u16*)(base + 3145728);            //  1572864 B
    float* c0g    = (float*)(base + 4718592);          //  1572864 B (fallback)
    float* c1g    = (float*)(base + 6291456);          //  1572864 B
    u16*   xpad   = (u16*)(base + 7864320);            //  4194304 B
    u16*   WtF0   = (u16*)(base + 12058624);           //   737280 B
    u16*   WtF1   = (u16*)(base + 12795904);           //  1327104 B
    u16*   hall   = (u16*)(base + 14123008);           // 50331648 B
    float* part   = (float*)(base + 64454656);         //   491520 B
    u16*   WdT    = (u16*)(base + 64946176);           // 31457280 B
    unsigned* bctrs  = (unsigned*)(base + 96403456);   //    16384 B
    unsigned* bepoch = (unsigned*)(base + 96419840);   //      256 B
    unsigned* reg8   = (unsigned*)(base + 96420096);   //     2048 B
    unsigned* xslots = (unsigned*)(base + 96422144);   //    32768 B

    hipMemsetAsync(base, 0, 7864320, stream);          // h/hbn/c states = 0
    hipMemsetAsync(bctrs, 0, 51456, stream);           // all barrier state

    prep_x  <<<1024, 256, 0, stream>>>(x, xpad);
    wtransF0<<<1440, 256, 0, stream>>>(Wx0, Wh0, WtF0);
    wtransF1<<<2592, 256, 0, stream>>>(Wx1, Wh1, WtF1);
    wtransD <<<6144, 256, 0, stream>>>(Wd, WdT);

    void* args[] = {
        (void*)&bctrs, (void*)&bepoch, (void*)&reg8, (void*)&xslots,
        (void*)&xpad, (void*)&h0b, (void*)&h1b, (void*)&h0bnb, (void*)&hall,
        (void*)&WtF0, (void*)&WtF1, (void*)&b0p, (void*)&b1p,
        (void*)&g0p, (void*)&be0p, (void*)&mu0p, (void*)&v0p,
        (void*)&g1p, (void*)&be1p, (void*)&mu1p, (void*)&v1p
    };
    hipError_t ce = hipLaunchCooperativeKernel((void*)fused, dim3(256),
                                               dim3(512), args, 0, stream);
    if (ce != hipSuccess) {
        (void)hipGetLastError();   // clear sticky error, use fallback path
        for (int t = -1; t < 64; ++t) {
            stepF<<<256, 512, 0, stream>>>(t, xpad, h0b, h1b, h0bnb, hall,
                                           WtF0, WtF1, b0p, b1p,
                                           g0p, be0p, mu0p, v0p,
                                           g1p, be1p, mu1p, v1p, c0g, c1g);
        }
    }

    dense_partial<<<768, 160, 0, stream>>>(hall, WdT, part);
    dense_reduce <<<1, 160, 0, stream>>>(part, bd, out);
}